// Round 4
// baseline (248.720 us; speedup 1.0000x reference)
//
#include <hip/hip_runtime.h>
#include <hip/hip_fp16.h>

#define D_FEAT      128
#define SCAN_B      1024
#define S_BIN       512      // edge slices for binning passes (2 blocks/CU)
#define BUCKET_BITS 7
#define BUCKET_SZ   128      // nodes per bucket
#define NB_MAX      1024     // max buckets (131072 nodes)
#define SORT_CAP    6144     // LDS edge buffer per bucket (mean 2048, max ~2400)

typedef float f32x4 __attribute__((ext_vector_type(4)));

// --- 1. fused per-slice bucket histograms of dst AND src (LDS only, no global atomics) ---
__global__ void binhist2_kernel(const int* __restrict__ src, const int* __restrict__ dst,
                                int* __restrict__ part2, int n_edges, int nb, int N2,
                                int slice_len) {
    __shared__ int hd[NB_MAX];
    __shared__ int hs[NB_MAX];
    int s = blockIdx.x;
    for (int i = threadIdx.x; i < nb; i += blockDim.x) { hd[i] = 0; hs[i] = 0; }
    __syncthreads();
    int beg = s * slice_len;
    int end = beg + slice_len; if (end > n_edges) end = n_edges;
    for (int i = beg + threadIdx.x; i < end; i += blockDim.x) {
        atomicAdd(&hd[dst[i] >> BUCKET_BITS], 1);
        atomicAdd(&hs[src[i] >> BUCKET_BITS], 1);
    }
    __syncthreads();
    for (int b = threadIdx.x; b < nb; b += blockDim.x) {
        part2[(size_t)b * S_BIN + s] = hd[b];                  // dst half
        part2[(size_t)(N2 + b * S_BIN) + s] = hs[b];           // src half
    }
}

// --- 2a. per-block exclusive scan IN PLACE, block totals to bsum ---
__global__ __launch_bounds__(SCAN_B) void scan1_kernel(int* __restrict__ data,
        int* __restrict__ bsum, int n) {
    __shared__ int sh[SCAN_B];
    int t = threadIdx.x;
    int g = blockIdx.x * SCAN_B + t;
    int v = (g < n) ? data[g] : 0;
    sh[t] = v;
    __syncthreads();
    for (int d = 1; d < SCAN_B; d <<= 1) {
        int x = (t >= d) ? sh[t - d] : 0;
        __syncthreads();
        sh[t] += x;
        __syncthreads();
    }
    if (g < n) data[g] = sh[t] - v;                            // local exclusive
    if (t == SCAN_B - 1) bsum[blockIdx.x] = sh[t];
}

// --- 2b. exclusive scan of block sums (single block); consumers add bsum[idx>>10] ---
__global__ __launch_bounds__(SCAN_B) void scan2_kernel(int* __restrict__ bsum, int nb) {
    __shared__ int sh[SCAN_B];
    int t = threadIdx.x;
    int v = (t < nb) ? bsum[t] : 0;
    sh[t] = v;
    __syncthreads();
    for (int d = 1; d < SCAN_B; d <<= 1) {
        int x = (t >= d) ? sh[t - d] : 0;
        __syncthreads();
        sh[t] += x;
        __syncthreads();
    }
    if (t < nb) bsum[t] = sh[t] - v;
}

// --- 3. scatter edges into bucket-grouped streams via LDS cursors (no global atomics).
//        colp: dst-bucketed, packs src | (dst&127)<<20.  colp_src: src-bucketed, src&127 bytes. ---
__global__ void binscatter2_kernel(const int* __restrict__ src, const int* __restrict__ dst,
                                   const int* __restrict__ loff, const int* __restrict__ bsum,
                                   int* __restrict__ colp, unsigned char* __restrict__ colp_src,
                                   int n_edges, int nb, int N2, int slice_len) {
    __shared__ int cd[NB_MAX];
    __shared__ int cs[NB_MAX];
    int s = blockIdx.x;
    for (int b = threadIdx.x; b < nb; b += blockDim.x) {
        size_t iD = (size_t)b * S_BIN + s;
        size_t iS = (size_t)N2 + (size_t)b * S_BIN + s;
        cd[b] = loff[iD] + bsum[iD >> 10];
        cs[b] = loff[iS] + bsum[iS >> 10] - n_edges;           // src half rebased
    }
    __syncthreads();
    int beg = s * slice_len;
    int end = beg + slice_len; if (end > n_edges) end = n_edges;
    for (int i = beg + threadIdx.x; i < end; i += blockDim.x) {
        int d = dst[i], sv = src[i];
        int pD = atomicAdd(&cd[d >> BUCKET_BITS], 1);          // native LDS int atomic
        colp[pD] = sv | ((d & (BUCKET_SZ - 1)) << 20);
        int pS = atomicAdd(&cs[sv >> BUCKET_BITS], 1);
        colp_src[pS] = (unsigned char)(sv & (BUCKET_SZ - 1));
    }
}

// --- 4. merged: blocks [0,nb) in-bucket counting sort -> per-node CSR + node_off;
//        blocks [nb,2nb) out-degree count from colp_src -> norm_l. ---
__global__ __launch_bounds__(256) void sortcount_kernel(
        int* __restrict__ colp, const unsigned char* __restrict__ colp_src,
        const int* __restrict__ loff, const int* __restrict__ bsum,
        int* __restrict__ node_off, float* __restrict__ norm_l,
        int n_nodes, int n_edges, int nb, int N2) {
    __shared__ int buf[SORT_CAP];
    __shared__ int cnt[BUCKET_SZ];
    __shared__ int sa[BUCKET_SZ];
    __shared__ int sb[BUCKET_SZ];
    int tid = threadIdx.x;

    if ((int)blockIdx.x >= nb) {
        // ---- countsrc part ----
        int b = blockIdx.x - nb;
        size_t iA = (size_t)N2 + (size_t)b * S_BIN;
        int beg = loff[iA] + bsum[iA >> 10] - n_edges;
        int end;
        if (b + 1 < nb) {
            size_t iB = (size_t)N2 + (size_t)(b + 1) * S_BIN;
            end = loff[iB] + bsum[iB >> 10] - n_edges;
        } else end = n_edges;
        if (tid < BUCKET_SZ) cnt[tid] = 0;
        __syncthreads();
        for (int i = beg + tid; i < end; i += blockDim.x)
            atomicAdd(&cnt[colp_src[i]], 1);
        __syncthreads();
        int node0 = b << BUCKET_BITS;
        int bn = n_nodes - node0; if (bn > BUCKET_SZ) bn = BUCKET_SZ;
        if (tid < bn) {
            int c = cnt[tid]; if (c < 1) c = 1;
            norm_l[node0 + tid] = rsqrtf((float)c);
        }
        return;
    }

    // ---- sort part ----
    int b = blockIdx.x;
    size_t iA = (size_t)b * S_BIN;
    int beg = loff[iA] + bsum[iA >> 10];
    int end;
    if (b + 1 < nb) {
        size_t iB = (size_t)(b + 1) * S_BIN;
        end = loff[iB] + bsum[iB >> 10];
    } else end = n_edges;
    int m = end - beg;                                         // ~2048 << SORT_CAP
    if (tid < BUCKET_SZ) cnt[tid] = 0;
    __syncthreads();
    for (int i = tid; i < m; i += blockDim.x) {
        int v = colp[beg + i];
        if (i < SORT_CAP) buf[i] = v;
        atomicAdd(&cnt[(v >> 20) & (BUCKET_SZ - 1)], 1);
    }
    __syncthreads();
    int* rp = sa; int* wp = sb;                                // inclusive scan, ping-pong
    if (tid < BUCKET_SZ) sa[tid] = cnt[tid];
    __syncthreads();
    for (int d = 1; d < BUCKET_SZ; d <<= 1) {
        if (tid < BUCKET_SZ) wp[tid] = rp[tid] + (tid >= d ? rp[tid - d] : 0);
        __syncthreads();
        int* t = rp; rp = wp; wp = t;
    }
    int node0 = b << BUCKET_BITS;
    int bn = n_nodes - node0; if (bn > BUCKET_SZ) bn = BUCKET_SZ;
    if (tid < BUCKET_SZ) {
        int ex = rp[tid] - cnt[tid];                           // exclusive
        wp[tid] = ex;                                          // cursors
        if (tid < bn) node_off[node0 + tid] = beg + ex;
    }
    if (b == nb - 1 && tid == 0) node_off[n_nodes] = end;
    __syncthreads();
    int mm = m < SORT_CAP ? m : SORT_CAP;
    for (int i = tid; i < mm; i += blockDim.x) {
        int v = buf[i];
        int p = atomicAdd(&wp[(v >> 20) & (BUCKET_SZ - 1)], 1);
        colp[beg + p] = v & 0xFFFFF;                           // src only (17 bits)
    }
}

// --- 5. fp16 pre-scaled features: feat16 = (half)(feat * norm_l[row]); NT feat loads ---
__global__ void convert_kernel(const float* __restrict__ feat, const float* __restrict__ norm_l,
                               __half* __restrict__ feat16, int n_nodes) {
    int t = blockIdx.x * blockDim.x + threadIdx.x;
    int total = n_nodes * (D_FEAT / 8);
    if (t >= total) return;
    float nl = norm_l[t >> 4];                                 // 16 threads per 128-elem row
    const f32x4* fp = (const f32x4*)feat + (size_t)t * 2;
    f32x4 a = __builtin_nontemporal_load(fp);
    f32x4 b = __builtin_nontemporal_load(fp + 1);
    __half2 h0 = __floats2half2_rn(a.x * nl, a.y * nl);
    __half2 h1 = __floats2half2_rn(a.z * nl, a.w * nl);
    __half2 h2 = __floats2half2_rn(b.x * nl, b.y * nl);
    __half2 h3 = __floats2half2_rn(b.z * nl, b.w * nl);
    uint4 o;
    o.x = *(unsigned int*)&h0; o.y = *(unsigned int*)&h1;
    o.z = *(unsigned int*)&h2; o.w = *(unsigned int*)&h3;
    ((uint4*)feat16)[t] = o;
}

// --- 6. CSR pull, 4 edges per vmem instruction:
//     wave = 2 nodes (32-lane halves); each half = 2 subgroups of 16 lanes;
//     subgroup loads a full 256 B row as uint4 (16 B/lane). One dwordx4 = 4 edges (1 KB).
//     Epilogue: shfl_xor(16) reduce, 2 NT dwordx4 stores per node. Zero atomics. ---
__global__ __launch_bounds__(256) void pull_csr_kernel(
        const __half* __restrict__ feat16, const int* __restrict__ col,
        const int* __restrict__ node_off, float* __restrict__ out, int n_nodes) {
    int lane = threadIdx.x & 63;
    int wid  = (int)(((long long)blockIdx.x * blockDim.x + threadIdx.x) >> 6);
    int h  = lane >> 5;            // node half
    int g  = (lane >> 4) & 1;      // edge subgroup within half
    int dl = lane & 15;            // dim lane (16 B of the row)
    int node = wid * 2 + h;
    bool nvalid = node < n_nodes;
    int nsafe = nvalid ? node : n_nodes - 1;
    int s = node_off[nsafe];
    int e = nvalid ? node_off[nsafe + 1] : s;
    int m = e - s;
    int om = __shfl_xor(m, 32, 64);                            // other half's count
    int mm = m > om ? m : om;                                  // wave-max

    float a0=0.f,a1=0.f,a2=0.f,a3=0.f,a4=0.f,a5=0.f,a6=0.f,a7=0.f;
    const uint4* rowb = (const uint4*)feat16;

    for (int base = 0; base < mm; base += 32) {
        int remh = m - base;                                   // this half's remaining
        int cl = lane & 31;
        int ci = cl;
        if (ci >= remh) ci = (remh > 0) ? remh - 1 : 0;        // clamp (unused lanes)
        int cv = col[s + base + ci];                           // coalesced 128 B/half chunk
        int lim = mm - base; if (lim > 32) lim = 32;
        for (int k = 0; k < lim; k += 2) {
            int srcl = (lane & 32) + k + g;
            int idx = __shfl(cv, srcl, 64);                    // broadcast within half
            if (base + k + g < m) {
                uint4 hv = rowb[((size_t)(unsigned)idx << 4) + dl];   // idx*256 B + dl*16
                float2 f;
                f = __half22float2(*(__half2*)&hv.x); a0 += f.x; a1 += f.y;
                f = __half22float2(*(__half2*)&hv.y); a2 += f.x; a3 += f.y;
                f = __half22float2(*(__half2*)&hv.z); a4 += f.x; a5 += f.y;
                f = __half22float2(*(__half2*)&hv.w); a6 += f.x; a7 += f.y;
            }
        }
    }

    // combine the two subgroups of each half
    a0 += __shfl_xor(a0, 16, 64); a1 += __shfl_xor(a1, 16, 64);
    a2 += __shfl_xor(a2, 16, 64); a3 += __shfl_xor(a3, 16, 64);
    a4 += __shfl_xor(a4, 16, 64); a5 += __shfl_xor(a5, 16, 64);
    a6 += __shfl_xor(a6, 16, 64); a7 += __shfl_xor(a7, 16, 64);

    if (nvalid && g == 0) {
        int c = m < 1 ? 1 : m;
        float nr = rsqrtf((float)c);
        f32x4 o0 = {a0 * nr, a1 * nr, a2 * nr, a3 * nr};
        f32x4 o1 = {a4 * nr, a5 * nr, a6 * nr, a7 * nr};
        f32x4* op = (f32x4*)(out + (size_t)node * D_FEAT) + dl * 2;
        __builtin_nontemporal_store(o0, op);
        __builtin_nontemporal_store(o1, op + 1);
    }
}

extern "C" void kernel_launch(void* const* d_in, const int* in_sizes, int n_in,
                              void* d_out, int out_size, void* d_ws, size_t ws_size,
                              hipStream_t stream) {
    const float* feat = (const float*)d_in[0];
    const int*   src  = (const int*)d_in[1];
    const int*   dst  = (const int*)d_in[2];
    float* out = (float*)d_out;

    const int n_nodes = in_sizes[0] / D_FEAT;                 // 100000
    const int n_edges = in_sizes[1];                          // 1600000
    const int nb = (n_nodes + BUCKET_SZ - 1) / BUCKET_SZ;     // 782
    const int N2 = nb * S_BIN;                                // 400384 per half
    const int NSCAN = 2 * N2;                                 // 800768
    const int sl = (n_edges + S_BIN - 1) / S_BIN;             // 3125

    // ws (~37.6 MB): node_off norm_l part2(in-place scan) bsum colp colp_src feat16
    auto alignup = [](size_t x) { return (x + 255) & ~(size_t)255; };
    char* p = (char*)d_ws;
    int*    node_off = (int*)p;            p += alignup((size_t)(n_nodes + 1) * 4);
    float*  norm_l   = (float*)p;          p += alignup((size_t)n_nodes * 4);
    int*    part2    = (int*)p;            p += alignup((size_t)NSCAN * 4);
    int*    bsum     = (int*)p;            p += alignup((size_t)SCAN_B * 4);
    int*    colp     = (int*)p;            p += alignup((size_t)n_edges * 4);
    unsigned char* colp_src = (unsigned char*)p; p += alignup((size_t)n_edges);
    __half* feat16   = (__half*)p;

    // 1. fused bucket histograms (dst + src)
    binhist2_kernel<<<S_BIN, 256, 0, stream>>>(src, dst, part2, n_edges, nb, N2, sl);

    // 2. two-level exclusive scan (in place + block sums); consumers add bsum themselves
    {
        int nsb = (NSCAN + SCAN_B - 1) / SCAN_B;              // 782
        scan1_kernel<<<nsb, SCAN_B, 0, stream>>>(part2, bsum, NSCAN);
        scan2_kernel<<<1, SCAN_B, 0, stream>>>(bsum, nsb);
    }

    // 3. bucket-grouped edge streams (LDS cursors)
    binscatter2_kernel<<<S_BIN, 256, 0, stream>>>(src, dst, part2, bsum, colp, colp_src,
                                                  n_edges, nb, N2, sl);

    // 4. merged in-bucket counting sort (-> node_off) + out-degree count (-> norm_l)
    sortcount_kernel<<<2 * nb, 256, 0, stream>>>(colp, colp_src, part2, bsum, node_off,
                                                 norm_l, n_nodes, n_edges, nb, N2);

    // 5. fp16 pre-scaled features
    {
        int total = n_nodes * (D_FEAT / 8);
        convert_kernel<<<(total + 255) / 256, 256, 0, stream>>>(feat, norm_l, feat16, n_nodes);
    }

    // 6. pull: one wave per 2 nodes, 4 edges per vmem instruction
    {
        long long waves = ((long long)n_nodes + 1) / 2;
        long long total = waves * 64;
        pull_csr_kernel<<<(int)((total + 255) / 256), 256, 0, stream>>>(feat16, colp, node_off,
                                                                        out, n_nodes);
    }
}